// Round 1
// baseline (4302.602 us; speedup 1.0000x reference)
//
#include <hip/hip_runtime.h>
#include <math.h>

constexpr int kB = 64, kN = 196, kENC = 2048, kDEC = 512, kE = 512, kATT = 512;
constexpr int kV = 32000, kT = 32, kTS = 31;
constexpr int kKIH = kE + kENC;        // 2560
constexpr int kKC  = kKIH + kDEC;      // 3072
constexpr int kG   = 4 * kDEC;         // 2048
constexpr int kSPLIT = 8, kKLEN = kKC / kSPLIT; // 384

__device__ __forceinline__ float sigmoidf_(float x){ return 1.f/(1.f+__expf(-x)); }

// ---------------- mean over N ----------------
__global__ void k_mean(const float* __restrict__ feat, float* __restrict__ meanf){
  int b = blockIdx.x, d = blockIdx.y*256 + threadIdx.x;
  const float* p = feat + (size_t)b*kN*kENC + d;
  float s = 0.f;
  for (int n=0;n<kN;n++) s += p[(size_t)n*kENC];
  meanf[b*kENC + d] = s * (1.f/kN);
}

// ---------------- h0 / c0 ----------------
__global__ __launch_bounds__(512) void k_init(const float* __restrict__ meanf,
                       const float* __restrict__ Wh, const float* __restrict__ bh,
                       const float* __restrict__ Wc, const float* __restrict__ bc,
                       float* __restrict__ h, float* __restrict__ c){
  __shared__ float mf[kENC];
  int b = blockIdx.x;
  for (int i=threadIdx.x;i<kENC;i+=512) mf[i] = meanf[b*kENC+i];
  __syncthreads();
  int j = threadIdx.x;
  const float* W  = blockIdx.y ? Wc : Wh;
  const float* bb = blockIdx.y ? bc : bh;
  float acc = bb[j];
  for (int k=0;k<kENC;k++) acc = fmaf(mf[k], W[k*kDEC + j], acc);
  (blockIdx.y ? c : h)[b*kDEC + j] = acc;
}

// ---------------- enc_att = features @ att_Wenc  (12544x2048 @ 2048x512) ----------------
__global__ __launch_bounds__(256) void k_encatt(const float* __restrict__ A,
                                                const float* __restrict__ Bw,
                                                float* __restrict__ C){
  __shared__ float As[16][64];
  __shared__ float Bs[16][64];
  int m0 = blockIdx.x*64, n0 = blockIdx.y*64;
  int tid = threadIdx.x;
  int tm = tid>>4, tn = tid&15;
  float acc[4][4] = {};
  int lm = tid>>2, lkc = tid&3;       // A-load: row lm, k-chunk lkc (4 k each)
  int lk = tid>>4, lnc = tid&15;      // B-load: k row lk, 4-col chunk lnc
  for (int k0=0;k0<kENC;k0+=16){
    float4 av = *(const float4*)(A + (size_t)(m0+lm)*kENC + k0 + lkc*4);
    float4 bv = *(const float4*)(Bw + (size_t)(k0+lk)*kDEC + n0 + lnc*4);
    __syncthreads();
    int ak = lkc*4;
    As[ak+0][lm]=av.x; As[ak+1][lm]=av.y; As[ak+2][lm]=av.z; As[ak+3][lm]=av.w;
    *(float4*)(&Bs[lk][lnc*4]) = bv;
    __syncthreads();
    #pragma unroll
    for (int kk=0;kk<16;kk++){
      float a_[4], b_[4];
      *(float4*)a_ = *(const float4*)(&As[kk][tm*4]);
      *(float4*)b_ = *(const float4*)(&Bs[kk][tn*4]);
      #pragma unroll
      for (int i=0;i<4;i++)
        #pragma unroll
        for (int j=0;j<4;j++)
          acc[i][j] = fmaf(a_[i], b_[j], acc[i][j]);
    }
  }
  #pragma unroll
  for (int i=0;i<4;i++){
    float4 o = make_float4(acc[i][0],acc[i][1],acc[i][2],acc[i][3]);
    *(float4*)(C + (size_t)(m0+tm*4+i)*kDEC + n0 + tn*4) = o;
  }
}

// ---------------- e[b][n] = tanh(enc_att + hWdec) . att_v ----------------
__global__ __launch_bounds__(256) void k_e(const float* __restrict__ encatt,
                   const float* __restrict__ hWdec,
                   const float* __restrict__ attv, float* __restrict__ e){
  int w = threadIdx.x>>6, lane = threadIdx.x&63;
  int r = blockIdx.x*4 + w;           // 0..12543
  int b = r/kN;
  const float* ea = encatt + (size_t)r*kATT;
  const float* hw = hWdec + b*kATT;
  float s = 0.f;
  #pragma unroll
  for (int i=0;i<8;i++){
    int a = lane + i*64;
    s = fmaf(tanhf(ea[a] + hw[a]), attv[a], s);
  }
  #pragma unroll
  for (int off=32;off;off>>=1) s += __shfl_xor(s, off, 64);
  if (lane==0) e[r] = s;
}

// ---------------- softmax(e) + context; writes alphas output ----------------
__global__ __launch_bounds__(256) void k_ctx(const float* __restrict__ e,
                     const float* __restrict__ feat,
                     float* __restrict__ lstm_in, float* __restrict__ alphas, int t){
  __shared__ float al[kN];
  __shared__ float red[256];
  int b = blockIdx.x, tid = threadIdx.x;
  float ev = (tid<kN) ? e[b*kN+tid] : -1e30f;
  red[tid] = ev; __syncthreads();
  for (int off=128;off;off>>=1){ if (tid<off) red[tid] = fmaxf(red[tid], red[tid+off]); __syncthreads(); }
  float mx = red[0]; __syncthreads();
  float ex = (tid<kN) ? __expf(ev-mx) : 0.f;
  red[tid] = ex; __syncthreads();
  for (int off=128;off;off>>=1){ if (tid<off) red[tid] += red[tid+off]; __syncthreads(); }
  float inv = 1.f/red[0];
  if (tid<kN){
    float a = ex*inv;
    al[tid] = a;
    if (blockIdx.y==0) alphas[((size_t)b*kTS + t)*kN + tid] = a;
  }
  __syncthreads();
  int d = blockIdx.y*256 + tid;
  const float* fp = feat + (size_t)b*kN*kENC + d;
  float acc = 0.f;
  for (int n=0;n<kN;n++) acc = fmaf(al[n], fp[(size_t)n*kENC], acc);
  lstm_in[b*kKC + kE + d] = acc;
}

// ---------------- gates GEMM (split-K): [64x3072] @ W_cat^T -> partials ----------------
__global__ __launch_bounds__(256) void k_gates(const float* __restrict__ lstm_in,
        const float* __restrict__ Wih, const float* __restrict__ Whh,
        float* __restrict__ gpart){
  __shared__ float As[32][64];
  __shared__ float Bs[32][64];
  int n0 = blockIdx.x*64, ks = blockIdx.y;
  int tid = threadIdx.x;
  int tm = tid>>4, tn = tid&15;
  float acc[4][4] = {};
  int am = tid>>2, akc = tid&3;   // A: row am, 8 k's starting akc*8
  int bj = tid>>2, bkc = tid&3;   // B: weight row n0+bj, 8 k's
  for (int kt=0; kt<kKLEN; kt+=32){
    int k0 = ks*kKLEN + kt;
    float4 a0 = *(const float4*)(lstm_in + am*kKC + k0 + akc*8);
    float4 a1 = *(const float4*)(lstm_in + am*kKC + k0 + akc*8 + 4);
    const float* wrow = (k0 < kKIH) ? (Wih + (size_t)(n0+bj)*kKIH + k0)
                                    : (Whh + (size_t)(n0+bj)*kDEC + (k0-kKIH));
    float4 b0 = *(const float4*)(wrow + bkc*8);
    float4 b1 = *(const float4*)(wrow + bkc*8 + 4);
    __syncthreads();
    int ak = akc*8;
    As[ak+0][am]=a0.x; As[ak+1][am]=a0.y; As[ak+2][am]=a0.z; As[ak+3][am]=a0.w;
    As[ak+4][am]=a1.x; As[ak+5][am]=a1.y; As[ak+6][am]=a1.z; As[ak+7][am]=a1.w;
    int bk = bkc*8;
    Bs[bk+0][bj]=b0.x; Bs[bk+1][bj]=b0.y; Bs[bk+2][bj]=b0.z; Bs[bk+3][bj]=b0.w;
    Bs[bk+4][bj]=b1.x; Bs[bk+5][bj]=b1.y; Bs[bk+6][bj]=b1.z; Bs[bk+7][bj]=b1.w;
    __syncthreads();
    #pragma unroll
    for (int kk=0;kk<32;kk++){
      float a_[4], b_[4];
      *(float4*)a_ = *(const float4*)(&As[kk][tm*4]);
      *(float4*)b_ = *(const float4*)(&Bs[kk][tn*4]);
      #pragma unroll
      for (int i=0;i<4;i++)
        #pragma unroll
        for (int j=0;j<4;j++)
          acc[i][j] = fmaf(a_[i], b_[j], acc[i][j]);
    }
  }
  #pragma unroll
  for (int i=0;i<4;i++)
    *(float4*)(gpart + ((size_t)ks*kB + tm*4+i)*kG + n0 + tn*4)
        = make_float4(acc[i][0],acc[i][1],acc[i][2],acc[i][3]);
}

// ---------------- LSTM pointwise + next-step x/h fill + hWdec ----------------
__global__ __launch_bounds__(512) void k_lstm(const float* __restrict__ gpart,
      const float* __restrict__ bih, const float* __restrict__ bhh,
      float* __restrict__ h, float* __restrict__ c,
      float* __restrict__ lstm_in,
      const float* __restrict__ emb, const int* __restrict__ captions,
      const float* __restrict__ Wdec, float* __restrict__ hWdec, int tnext){
  __shared__ float hl[kDEC];
  int b = blockIdx.x, d = threadIdx.x;
  float gi=0.f, gf=0.f, gg=0.f, go=0.f;
  for (int ks=0;ks<kSPLIT;ks++){
    const float* gp = gpart + ((size_t)ks*kB + b)*kG;
    gi += gp[d]; gf += gp[kDEC+d]; gg += gp[2*kDEC+d]; go += gp[3*kDEC+d];
  }
  gi += bih[d]        + bhh[d];
  gf += bih[kDEC+d]   + bhh[kDEC+d];
  gg += bih[2*kDEC+d] + bhh[2*kDEC+d];
  go += bih[3*kDEC+d] + bhh[3*kDEC+d];
  float cn = sigmoidf_(gf)*c[b*kDEC+d] + sigmoidf_(gi)*tanhf(gg);
  float hn = sigmoidf_(go)*tanhf(cn);
  c[b*kDEC+d] = cn; h[b*kDEC+d] = hn;
  hl[d] = hn;
  lstm_in[b*kKC + kKIH + d] = hn;
  lstm_in[b*kKC + d] = emb[(size_t)captions[b*kT + tnext]*kE + d];
  __syncthreads();
  float acc = 0.f;
  for (int k=0;k<kDEC;k++) acc = fmaf(hl[k], Wdec[k*kATT + d], acc);
  hWdec[b*kATT + d] = acc;
}

// ---------------- initial x0/h0 fill + hWdec0 ----------------
__global__ __launch_bounds__(512) void k_prep(const float* __restrict__ h, float* __restrict__ lstm_in,
      const float* __restrict__ emb, const int* __restrict__ captions,
      const float* __restrict__ Wdec, float* __restrict__ hWdec){
  __shared__ float hl[kDEC];
  int b = blockIdx.x, d = threadIdx.x;
  float hv = h[b*kDEC+d];
  hl[d] = hv;
  lstm_in[b*kKC + kKIH + d] = hv;
  lstm_in[b*kKC + d] = emb[(size_t)captions[b*kT]*kE + d];
  __syncthreads();
  float acc = 0.f;
  for (int k=0;k<kDEC;k++) acc = fmaf(hl[k], Wdec[k*kATT + d], acc);
  hWdec[b*kATT + d] = acc;
}

// ---------------- out = h @ out_W + out_b ----------------
__global__ __launch_bounds__(256) void k_out(const float* __restrict__ h,
      const float* __restrict__ W, const float* __restrict__ bias,
      float* __restrict__ preds, int t){
  __shared__ float hs[16][kDEC];
  int v = blockIdx.x*256 + threadIdx.x;
  int b0 = blockIdx.y*16;
  {
    const float4* src = (const float4*)(h + b0*kDEC);
    float4* dst = (float4*)(&hs[0][0]);
    for (int i=threadIdx.x; i<16*kDEC/4; i+=256) dst[i] = src[i];
  }
  __syncthreads();
  float acc[16];
  float bb = bias[v];
  #pragma unroll
  for (int i=0;i<16;i++) acc[i] = bb;
  for (int k=0;k<kDEC;k+=4){
    float w0 = W[(size_t)(k+0)*kV + v];
    float w1 = W[(size_t)(k+1)*kV + v];
    float w2 = W[(size_t)(k+2)*kV + v];
    float w3 = W[(size_t)(k+3)*kV + v];
    #pragma unroll
    for (int i=0;i<16;i++){
      float4 h4 = *(const float4*)(&hs[i][k]);
      acc[i] = fmaf(h4.x, w0, fmaf(h4.y, w1, fmaf(h4.z, w2, fmaf(h4.w, w3, acc[i]))));
    }
  }
  #pragma unroll
  for (int i=0;i<16;i++)
    preds[((size_t)(b0+i)*kTS + t)*kV + v] = acc[i];
}

extern "C" void kernel_launch(void* const* d_in, const int* in_sizes, int n_in,
                              void* d_out, int out_size, void* d_ws, size_t ws_size,
                              hipStream_t stream) {
  const float* feat     = (const float*)d_in[0];
  const int*   captions = (const int*)  d_in[1];
  const float* emb      = (const float*)d_in[2];
  const float* attWenc  = (const float*)d_in[3];
  const float* attWdec  = (const float*)d_in[4];
  const float* attv     = (const float*)d_in[5];
  const float* ihW      = (const float*)d_in[6];
  const float* ihb      = (const float*)d_in[7];
  const float* icW      = (const float*)d_in[8];
  const float* icb      = (const float*)d_in[9];
  const float* Wih      = (const float*)d_in[10];
  const float* Whh      = (const float*)d_in[11];
  const float* bih      = (const float*)d_in[12];
  const float* bhh      = (const float*)d_in[13];
  const float* outW     = (const float*)d_in[14];
  const float* outb     = (const float*)d_in[15];

  float* preds  = (float*)d_out;                       // [64][31][32000]
  float* alphas = preds + (size_t)kB*kTS*kV;           // [64][31][196]

  float* ws      = (float*)d_ws;
  float* enc_att = ws;                                  // 12544*512 = 6,422,528
  float* meanf   = enc_att + (size_t)kB*kN*kATT;        // 131072
  float* h       = meanf   + (size_t)kB*kENC;           // 32768
  float* c       = h       + (size_t)kB*kDEC;           // 32768
  float* hWdec   = c       + (size_t)kB*kDEC;           // 32768
  float* evec    = hWdec   + (size_t)kB*kATT;           // 12544
  float* lstm_in = evec    + (size_t)kB*kN;             // 196608
  float* gpart   = lstm_in + (size_t)kB*kKC;            // 8*64*2048

  k_mean<<<dim3(kB, kENC/256), 256, 0, stream>>>(feat, meanf);
  k_init<<<dim3(kB, 2), 512, 0, stream>>>(meanf, ihW, ihb, icW, icb, h, c);
  k_encatt<<<dim3((kB*kN)/64, kATT/64), 256, 0, stream>>>(feat, attWenc, enc_att);
  k_prep<<<kB, 512, 0, stream>>>(h, lstm_in, emb, captions, attWdec, hWdec);

  for (int t = 0; t < kTS; ++t) {
    k_e<<<(kB*kN)/4, 256, 0, stream>>>(enc_att, hWdec, attv, evec);
    k_ctx<<<dim3(kB, kENC/256), 256, 0, stream>>>(evec, feat, lstm_in, alphas, t);
    k_gates<<<dim3(kG/64, kSPLIT), 256, 0, stream>>>(lstm_in, Wih, Whh, gpart);
    k_lstm<<<kB, 512, 0, stream>>>(gpart, bih, bhh, h, c, lstm_in, emb, captions,
                                   attWdec, hWdec, t+1);
    k_out<<<dim3(kV/256, kB/16), 256, 0, stream>>>(h, outW, outb, preds, t);
  }
}

// Round 2
// 2648.385 us; speedup vs baseline: 1.6246x; 1.6246x over previous
//
#include <hip/hip_runtime.h>
#include <math.h>

constexpr int kB = 64, kN = 196, kENC = 2048, kDEC = 512, kE = 512, kATT = 512;
constexpr int kV = 32000, kT = 32, kTS = 31;
constexpr int kKIH = kE + kENC;        // 2560
constexpr int kKC  = kKIH + kDEC;      // 3072
constexpr int kG   = 4 * kDEC;         // 2048
constexpr int kSPL = 8, kKSP = kKC / kSPL; // 384

typedef __attribute__((ext_vector_type(8))) short bf8;
typedef __attribute__((ext_vector_type(4))) float f4;

__device__ __forceinline__ f4 mfma16(bf8 a, bf8 b, f4 c){
  asm("v_mfma_f32_16x16x32_bf16 %0, %1, %2, %0" : "+v"(c) : "v"(a), "v"(b));
  return c;
}
__device__ __forceinline__ float bf2f(unsigned short u){
  return __uint_as_float(((unsigned)u) << 16);
}
__device__ __forceinline__ unsigned short f2b(float f){
  unsigned u = __float_as_uint(f);
  u += 0x7fffu + ((u >> 16) & 1u);
  return (unsigned short)(u >> 16);
}
__device__ __forceinline__ float th_(float x){          // tanh
  float e2 = __expf(2.f * x);
  return 1.f - 2.f * __builtin_amdgcn_rcpf(e2 + 1.f);
}
__device__ __forceinline__ float sg_(float x){          // sigmoid
  return __builtin_amdgcn_rcpf(1.f + __expf(-x));
}

// ---------------- fp32 -> bf16 bulk convert (8 elems/thread) ----------------
__global__ void k_cvt(const float* __restrict__ src, unsigned short* __restrict__ dst, int n8){
  int i = blockIdx.x * 256 + threadIdx.x;
  if (i >= n8) return;
  float4 a = ((const float4*)src)[2 * i];
  float4 b = ((const float4*)src)[2 * i + 1];
  union { unsigned short u[8]; uint4 v; } t;
  t.u[0] = f2b(a.x); t.u[1] = f2b(a.y); t.u[2] = f2b(a.z); t.u[3] = f2b(a.w);
  t.u[4] = f2b(b.x); t.u[5] = f2b(b.y); t.u[6] = f2b(b.z); t.u[7] = f2b(b.w);
  ((uint4*)dst)[i] = t.v;
}

// ---------------- fp32 [R][C] -> bf16 [C][R] tiled transpose ----------------
__global__ __launch_bounds__(256) void k_tcvt(const float* __restrict__ src,
                                              unsigned short* __restrict__ dst, int R, int C){
  __shared__ float t[32][33];
  int c0 = blockIdx.x * 32, r0 = blockIdx.y * 32;
  int tx = threadIdx.x & 31, ty = threadIdx.x >> 5;   // ty 0..7
  #pragma unroll
  for (int j = 0; j < 4; j++)
    t[ty + 8*j][tx] = src[(size_t)(r0 + ty + 8*j) * C + c0 + tx];
  __syncthreads();
  #pragma unroll
  for (int j = 0; j < 4; j++)
    dst[(size_t)(c0 + ty + 8*j) * R + r0 + tx] = f2b(t[tx][ty + 8*j]);
}

// ---------------- mean over N (fp32) ----------------
__global__ void k_mean(const float* __restrict__ feat, float* __restrict__ meanf){
  int b = blockIdx.x, d = blockIdx.y * 256 + threadIdx.x;
  const float* p = feat + (size_t)b * kN * kENC + d;
  float s = 0.f;
  for (int n = 0; n < kN; n++) s += p[(size_t)n * kENC];
  meanf[b * kENC + d] = s * (1.f / kN);
}

// ---------------- h0 / c0 ----------------
__global__ __launch_bounds__(512) void k_init(const float* __restrict__ meanf,
                       const float* __restrict__ Wh, const float* __restrict__ bh,
                       const float* __restrict__ Wc, const float* __restrict__ bc,
                       float* __restrict__ h, float* __restrict__ c){
  __shared__ float mf[kENC];
  int b = blockIdx.x;
  for (int i = threadIdx.x; i < kENC; i += 512) mf[i] = meanf[b * kENC + i];
  __syncthreads();
  int j = threadIdx.x;
  const float* W  = blockIdx.y ? Wc : Wh;
  const float* bb = blockIdx.y ? bc : bh;
  float acc = bb[j];
  for (int k = 0; k < kENC; k++) acc = fmaf(mf[k], W[k * kDEC + j], acc);
  (blockIdx.y ? c : h)[b * kDEC + j] = acc;
}

// ---------------- enc_att = featb @ attWT^T  -> bf16 [12544][512] ----------------
__global__ __launch_bounds__(256) void k_encatt(const unsigned short* __restrict__ A,   // [12544][2048]
                                                const unsigned short* __restrict__ Bt,  // [512][2048]
                                                unsigned short* __restrict__ Cb){       // [12544][512]
  int w = threadIdx.x >> 6, lane = threadIdx.x & 63;
  int m0 = blockIdx.x * 128 + w * 32, n0 = blockIdx.y * 64;
  int lr = lane & 15, lk = (lane >> 4) * 8;
  f4 acc[2][4] = {};
  const unsigned short* Ap = A  + (size_t)(m0 + lr) * kENC + lk;
  const unsigned short* Bp = Bt + (size_t)(n0 + lr) * kENC + lk;
  for (int k0 = 0; k0 < kENC; k0 += 32){
    bf8 a0 = *(const bf8*)(Ap + k0);
    bf8 a1 = *(const bf8*)(Ap + 16 * kENC + k0);
    bf8 b0 = *(const bf8*)(Bp + k0);
    bf8 b1 = *(const bf8*)(Bp + 16 * kENC + k0);
    bf8 b2 = *(const bf8*)(Bp + 32 * kENC + k0);
    bf8 b3 = *(const bf8*)(Bp + 48 * kENC + k0);
    acc[0][0] = mfma16(a0, b0, acc[0][0]); acc[0][1] = mfma16(a0, b1, acc[0][1]);
    acc[0][2] = mfma16(a0, b2, acc[0][2]); acc[0][3] = mfma16(a0, b3, acc[0][3]);
    acc[1][0] = mfma16(a1, b0, acc[1][0]); acc[1][1] = mfma16(a1, b1, acc[1][1]);
    acc[1][2] = mfma16(a1, b2, acc[1][2]); acc[1][3] = mfma16(a1, b3, acc[1][3]);
  }
  asm volatile("s_nop 7\n\ts_nop 7");
  int orow = (lane >> 4) * 4;
  #pragma unroll
  for (int mt = 0; mt < 2; mt++)
    #pragma unroll
    for (int nt = 0; nt < 4; nt++)
      #pragma unroll
      for (int r = 0; r < 4; r++)
        Cb[(size_t)(m0 + mt*16 + orow + r) * kATT + n0 + nt*16 + lr] = f2b(acc[mt][nt][r]);
}

// ---------------- e[r] = tanh(enc_att + hWdec) . att_v ----------------
__global__ __launch_bounds__(256) void k_e(const unsigned short* __restrict__ EA,
                   const float* __restrict__ hWdec,
                   const float* __restrict__ attv, float* __restrict__ e){
  int w = threadIdx.x >> 6, lane = threadIdx.x & 63;
  int r = blockIdx.x * 4 + w;
  int b = r / kN;
  bf8 ev = *(const bf8*)(EA + (size_t)r * kATT + lane * 8);
  const float* hw = hWdec + b * kATT + lane * 8;
  const float* av = attv + lane * 8;
  float4 h0 = *(const float4*)hw, h1 = *(const float4*)(hw + 4);
  float4 v0 = *(const float4*)av, v1 = *(const float4*)(av + 4);
  float s = 0.f;
  s = fmaf(th_(bf2f((unsigned short)ev[0]) + h0.x), v0.x, s);
  s = fmaf(th_(bf2f((unsigned short)ev[1]) + h0.y), v0.y, s);
  s = fmaf(th_(bf2f((unsigned short)ev[2]) + h0.z), v0.z, s);
  s = fmaf(th_(bf2f((unsigned short)ev[3]) + h0.w), v0.w, s);
  s = fmaf(th_(bf2f((unsigned short)ev[4]) + h1.x), v1.x, s);
  s = fmaf(th_(bf2f((unsigned short)ev[5]) + h1.y), v1.y, s);
  s = fmaf(th_(bf2f((unsigned short)ev[6]) + h1.z), v1.z, s);
  s = fmaf(th_(bf2f((unsigned short)ev[7]) + h1.w), v1.w, s);
  #pragma unroll
  for (int off = 32; off; off >>= 1) s += __shfl_xor(s, off, 64);
  if (lane == 0) e[r] = s;
}

// ---------------- softmax + context(bf16) + alphas ----------------
__global__ __launch_bounds__(256) void k_ctx(const float* __restrict__ e,
                     const unsigned short* __restrict__ featb,
                     unsigned short* __restrict__ Xb, float* __restrict__ alphas, int t){
  __shared__ float al[kN];
  __shared__ float red[256];
  int b = blockIdx.x, tid = threadIdx.x;
  float ev = (tid < kN) ? e[b * kN + tid] : -1e30f;
  red[tid] = ev; __syncthreads();
  for (int off = 128; off; off >>= 1){ if (tid < off) red[tid] = fmaxf(red[tid], red[tid + off]); __syncthreads(); }
  float mx = red[0]; __syncthreads();
  float ex = (tid < kN) ? __expf(ev - mx) : 0.f;
  red[tid] = ex; __syncthreads();
  for (int off = 128; off; off >>= 1){ if (tid < off) red[tid] += red[tid + off]; __syncthreads(); }
  float inv = 1.f / red[0];
  if (tid < kN){
    float a = ex * inv;
    al[tid] = a;
    if (blockIdx.y == 0) alphas[((size_t)b * kTS + t) * kN + tid] = a;
  }
  __syncthreads();
  int d = blockIdx.y * 512 + tid * 2;
  const unsigned short* fp = featb + (size_t)b * kN * kENC + d;
  float c0 = 0.f, c1 = 0.f;
  #pragma unroll 4
  for (int n = 0; n < kN; n++){
    unsigned u = *(const unsigned*)(fp + (size_t)n * kENC);
    float a = al[n];
    c0 = fmaf(bf2f((unsigned short)(u & 0xffffu)), a, c0);
    c1 = fmaf(bf2f((unsigned short)(u >> 16)), a, c1);
  }
  unsigned o = ((unsigned)f2b(c1) << 16) | (unsigned)f2b(c0);
  *(unsigned*)(Xb + (size_t)b * kKC + kE + d) = o;
}

// ---------------- gates GEMM split-K: gpart[ks][64][2048] ----------------
__global__ __launch_bounds__(256) void k_gates(const unsigned short* __restrict__ X,   // [64][3072]
        const unsigned short* __restrict__ Wih, const unsigned short* __restrict__ Whh,
        float* __restrict__ gpart){
  int w = threadIdx.x >> 6, lane = threadIdx.x & 63;
  int n0 = blockIdx.x * 64 + w * 16, ks = blockIdx.y;
  int lr = lane & 15, lk = (lane >> 4) * 8;
  int nrow = n0 + lr;
  f4 acc[4] = {};
  const unsigned short* Xp = X + (size_t)lr * kKC + lk;
  for (int kt = 0; kt < kKSP; kt += 32){
    int kk = ks * kKSP + kt + lk;
    bf8 a0 = *(const bf8*)(Xp + ks * kKSP + kt);
    bf8 a1 = *(const bf8*)(Xp + 16 * kKC + ks * kKSP + kt);
    bf8 a2 = *(const bf8*)(Xp + 32 * kKC + ks * kKSP + kt);
    bf8 a3 = *(const bf8*)(Xp + 48 * kKC + ks * kKSP + kt);
    const unsigned short* bp = (kk < kKIH) ? (Wih + (size_t)nrow * kKIH + kk)
                                           : (Whh + (size_t)nrow * kDEC + (kk - kKIH));
    bf8 b = *(const bf8*)bp;
    acc[0] = mfma16(a0, b, acc[0]); acc[1] = mfma16(a1, b, acc[1]);
    acc[2] = mfma16(a2, b, acc[2]); acc[3] = mfma16(a3, b, acc[3]);
  }
  asm volatile("s_nop 7\n\ts_nop 7");
  float* gp = gpart + (size_t)ks * kB * kG;
  int orow = (lane >> 4) * 4;
  #pragma unroll
  for (int mt = 0; mt < 4; mt++)
    #pragma unroll
    for (int r = 0; r < 4; r++)
      gp[(size_t)(mt*16 + orow + r) * kG + n0 + lr] = acc[mt][r];
}

// ---------------- LSTM pointwise + next x/h (bf16) + hWdec ----------------
__global__ __launch_bounds__(512) void k_lstm(const float* __restrict__ gpart,
      const float* __restrict__ bih, const float* __restrict__ bhh,
      float* __restrict__ c, unsigned short* __restrict__ Xb,
      const float* __restrict__ emb, const int* __restrict__ captions,
      const float* __restrict__ Wdec, float* __restrict__ hWdec, int tnext){
  __shared__ float hl[kDEC];
  int b = blockIdx.x, d = threadIdx.x;
  float gi = 0.f, gf = 0.f, gg = 0.f, go = 0.f;
  for (int ks = 0; ks < kSPL; ks++){
    const float* gp = gpart + ((size_t)ks * kB + b) * kG;
    gi += gp[d]; gf += gp[kDEC + d]; gg += gp[2*kDEC + d]; go += gp[3*kDEC + d];
  }
  gi += bih[d]          + bhh[d];
  gf += bih[kDEC + d]   + bhh[kDEC + d];
  gg += bih[2*kDEC + d] + bhh[2*kDEC + d];
  go += bih[3*kDEC + d] + bhh[3*kDEC + d];
  float cn = sg_(gf) * c[b*kDEC + d] + sg_(gi) * th_(gg);
  float hn = sg_(go) * th_(cn);
  c[b*kDEC + d] = cn;
  hl[d] = hn;
  Xb[(size_t)b * kKC + kKIH + d] = f2b(hn);
  Xb[(size_t)b * kKC + d] = f2b(emb[(size_t)captions[b*kT + tnext] * kE + d]);
  __syncthreads();
  float a = 0.f;
  for (int k = 0; k < kDEC; k++) a = fmaf(hl[k], Wdec[(size_t)k * kATT + d], a);
  hWdec[b * kATT + d] = a;
}

// ---------------- initial x0/h0 (bf16) + hWdec0 ----------------
__global__ __launch_bounds__(512) void k_prep(const float* __restrict__ h0,
      unsigned short* __restrict__ Xb, const float* __restrict__ emb,
      const int* __restrict__ captions,
      const float* __restrict__ Wdec, float* __restrict__ hWdec){
  __shared__ float hl[kDEC];
  int b = blockIdx.x, d = threadIdx.x;
  float hv = h0[b*kDEC + d];
  hl[d] = hv;
  Xb[(size_t)b * kKC + kKIH + d] = f2b(hv);
  Xb[(size_t)b * kKC + d] = f2b(emb[(size_t)captions[b*kT] * kE + d]);
  __syncthreads();
  float a = 0.f;
  for (int k = 0; k < kDEC; k++) a = fmaf(hl[k], Wdec[(size_t)k * kATT + d], a);
  hWdec[b * kATT + d] = a;
}

// ---------------- out = h @ out_W + out_b (MFMA) ----------------
__global__ __launch_bounds__(256) void k_out(const unsigned short* __restrict__ Xh,  // Xb + kKIH
        const unsigned short* __restrict__ Wt,  // [32000][512]
        const float* __restrict__ bias, float* __restrict__ preds, int t){
  int w = threadIdx.x >> 6, lane = threadIdx.x & 63;
  int n0 = blockIdx.x * 64 + w * 16;
  int lr = lane & 15, lk = (lane >> 4) * 8;
  float bv = bias[n0 + lr];
  f4 bvv = {bv, bv, bv, bv};
  f4 acc[4] = {bvv, bvv, bvv, bvv};
  const unsigned short* Wp = Wt + (size_t)(n0 + lr) * kDEC + lk;
  const unsigned short* Xp = Xh + (size_t)lr * kKC + lk;
  for (int k0 = 0; k0 < kDEC; k0 += 32){
    bf8 b  = *(const bf8*)(Wp + k0);
    bf8 a0 = *(const bf8*)(Xp + k0);
    bf8 a1 = *(const bf8*)(Xp + 16 * kKC + k0);
    bf8 a2 = *(const bf8*)(Xp + 32 * kKC + k0);
    bf8 a3 = *(const bf8*)(Xp + 48 * kKC + k0);
    acc[0] = mfma16(a0, b, acc[0]); acc[1] = mfma16(a1, b, acc[1]);
    acc[2] = mfma16(a2, b, acc[2]); acc[3] = mfma16(a3, b, acc[3]);
  }
  asm volatile("s_nop 7\n\ts_nop 7");
  int orow = (lane >> 4) * 4;
  #pragma unroll
  for (int mt = 0; mt < 4; mt++)
    #pragma unroll
    for (int r = 0; r < 4; r++){
      int bb = mt*16 + orow + r;
      preds[((size_t)bb * kTS + t) * kV + n0 + lr] = acc[mt][r];
    }
}

extern "C" void kernel_launch(void* const* d_in, const int* in_sizes, int n_in,
                              void* d_out, int out_size, void* d_ws, size_t ws_size,
                              hipStream_t stream) {
  const float* feat     = (const float*)d_in[0];
  const int*   captions = (const int*)  d_in[1];
  const float* emb      = (const float*)d_in[2];
  const float* attWenc  = (const float*)d_in[3];
  const float* attWdec  = (const float*)d_in[4];
  const float* attv     = (const float*)d_in[5];
  const float* ihW      = (const float*)d_in[6];
  const float* ihb      = (const float*)d_in[7];
  const float* icW      = (const float*)d_in[8];
  const float* icb      = (const float*)d_in[9];
  const float* Wih      = (const float*)d_in[10];
  const float* Whh      = (const float*)d_in[11];
  const float* bih      = (const float*)d_in[12];
  const float* bhh      = (const float*)d_in[13];
  const float* outW     = (const float*)d_in[14];
  const float* outb     = (const float*)d_in[15];

  float* preds  = (float*)d_out;                       // [64][31][32000]
  float* alphas = preds + (size_t)kB * kTS * kV;       // [64][31][196]

  char* p = (char*)d_ws;
  unsigned short* featb  = (unsigned short*)p; p += (size_t)kB*kN*kENC*2;   // 51,380,224
  unsigned short* outWb  = (unsigned short*)p; p += (size_t)kV*kDEC*2;      // 32,768,000
  unsigned short* Wihb   = (unsigned short*)p; p += (size_t)kG*kKIH*2;      // 10,485,760
  unsigned short* Whhb   = (unsigned short*)p; p += (size_t)kG*kDEC*2;      //  2,097,152
  unsigned short* attWT  = (unsigned short*)p; p += (size_t)kATT*kENC*2;    //  2,097,152
  unsigned short* encattb= (unsigned short*)p; p += (size_t)kB*kN*kATT*2;   // 12,845,056
  unsigned short* Xb     = (unsigned short*)p; p += (size_t)kB*kKC*2;       //    393,216
  float* gpart = (float*)p; p += (size_t)kSPL*kB*kG*4;                      //  4,194,304
  float* meanf = (float*)p; p += (size_t)kB*kENC*4;
  float* h0    = (float*)p; p += (size_t)kB*kDEC*4;
  float* cbuf  = (float*)p; p += (size_t)kB*kDEC*4;
  float* hWdec = (float*)p; p += (size_t)kB*kATT*4;
  float* evec  = (float*)p; p += (size_t)kB*kN*4;

  // one-time conversions
  k_cvt<<<(kB*kN*kENC/8 + 255)/256, 256, 0, stream>>>(feat, featb, kB*kN*kENC/8);
  k_cvt<<<(kG*kKIH/8 + 255)/256, 256, 0, stream>>>(Wih, Wihb, kG*kKIH/8);
  k_cvt<<<(kG*kDEC/8 + 255)/256, 256, 0, stream>>>(Whh, Whhb, kG*kDEC/8);
  k_tcvt<<<dim3(kATT/32, kENC/32), 256, 0, stream>>>(attWenc, attWT, kENC, kATT);
  k_tcvt<<<dim3(kV/32, kDEC/32), 256, 0, stream>>>(outW, outWb, kDEC, kV);

  k_mean<<<dim3(kB, kENC/256), 256, 0, stream>>>(feat, meanf);
  k_init<<<dim3(kB, 2), 512, 0, stream>>>(meanf, ihW, ihb, icW, icb, h0, cbuf);
  k_encatt<<<dim3(kB*kN/128, kATT/64), 256, 0, stream>>>(featb, attWT, encattb);
  k_prep<<<kB, 512, 0, stream>>>(h0, Xb, emb, captions, attWdec, hWdec);

  for (int t = 0; t < kTS; ++t) {
    k_e<<<kB*kN/4, 256, 0, stream>>>(encattb, hWdec, attv, evec);
    k_ctx<<<dim3(kB, kENC/512), 256, 0, stream>>>(evec, featb, Xb, alphas, t);
    k_gates<<<dim3(kG/64, kSPL), 256, 0, stream>>>(Xb, Wihb, Whhb, gpart);
    k_lstm<<<kB, 512, 0, stream>>>(gpart, bih, bhh, cbuf, Xb, emb, captions,
                                   attWdec, hWdec, t + 1);
    k_out<<<kV/64, 256, 0, stream>>>(Xb + kKIH, outWb, outb, preds, t);
  }
}